// Round 9
// baseline (1619.840 us; speedup 1.0000x reference)
//
#include <hip/hip_runtime.h>
#include <math.h>

#define EPSV 1e-5f
#define SBLK 512      // edge slices for count/append
#define WNODES 256    // nodes per window (64KB fp32 LDS accumulator)

typedef _Float16 h16;
typedef _Float16 half8 __attribute__((ext_vector_type(8)));
typedef float f32x4 __attribute__((ext_vector_type(4)));

static __device__ __forceinline__ float h2f(unsigned int u16) {
  unsigned short s = (unsigned short)u16;
  h16 h;
  __builtin_memcpy(&h, &s, 2);
  return (float)h;
}

// ---------------------------------------------------------------- per-(slice,window) edge counts
// cnt512[s*nw + w] = #edges in slice s with dst in window w. No atomics to global.
__global__ __launch_bounds__(256) void k_cnt(const int* __restrict__ ei,
                                             int* __restrict__ cnt512, int E, int nw) {
  __shared__ int hist[512];
  int s = blockIdx.x;
  for (int i = threadIdx.x; i < nw; i += 256) hist[i] = 0;
  __syncthreads();
  long long elo = (long long)s * E / SBLK, ehi = (long long)(s + 1) * E / SBLK;
  for (long long i = elo + threadIdx.x; i < ehi; i += 256)
    atomicAdd(&hist[ei[E + i] >> 8], 1);
  __syncthreads();
  for (int i = threadIdx.x; i < nw; i += 256) cnt512[s * nw + i] = hist[i];
}

// ---------------------------------------------------------------- scan: window bases + per-(slice,window) bases (in-place)
__global__ __launch_bounds__(512) void k_scan2(int* __restrict__ cnt512,
                                               int* __restrict__ woffs, int E, int nw) {
  int w = threadIdx.x;
  int tot = 0;
  if (w < nw) {
#pragma unroll 8
    for (int s = 0; s < SBLK; ++s) tot += cnt512[s * nw + w];  // coalesced across threads
  }
  __shared__ int sh[512];
  sh[w] = tot;
  __syncthreads();
  for (int off = 1; off < 512; off <<= 1) {
    int u = (w >= off) ? sh[w - off] : 0;
    __syncthreads();
    sh[w] += u;
    __syncthreads();
  }
  int base = sh[w] - tot;  // exclusive prefix
  if (w < nw) {
    woffs[w] = base;
    int run = base;
    for (int s = 0; s < SBLK; ++s) {
      int c = cnt512[s * nw + w];
      cnt512[s * nw + w] = run;  // becomes per-(slice,window) base
      run += c;
    }
  }
  if (w == 0) woffs[nw] = E;
}

// ---------------------------------------------------------------- append: bucket[pos] = src | (dst_lo<<24), window-grouped
// Cursors are BLOCK-LOCAL (each (s,w) segment owned by one block) -> no global atomics.
__global__ __launch_bounds__(256) void k_append(const int* __restrict__ ei,
                                                const int* __restrict__ base512,
                                                int* __restrict__ bucket, int E, int nw) {
  __shared__ int cur[512];
  int s = blockIdx.x;
  for (int i = threadIdx.x; i < nw; i += 256) cur[i] = base512[s * nw + i];
  __syncthreads();
  long long elo = (long long)s * E / SBLK, ehi = (long long)(s + 1) * E / SBLK;
  for (long long i = elo + threadIdx.x; i < ehi; i += 256) {
    int d = ei[E + i];
    int src = ei[i];
    int pos = atomicAdd(&cur[d >> 8], 1);            // LDS cursor
    bucket[pos] = src | ((d & 255) << 24);           // src<2^24, dst_lo 8 bits
  }
}

// ---------------------------------------------------------------- degree from bucket -> dinv
__global__ __launch_bounds__(256) void k_degw(const int* __restrict__ bucket,
                                              const int* __restrict__ woffs,
                                              float* __restrict__ dinv, int N) {
  __shared__ int cnt[WNODES];
  int w = blockIdx.x;
  cnt[threadIdx.x] = 0;
  __syncthreads();
  int lo = woffs[w], hi = woffs[w + 1];
  for (int i = lo + threadIdx.x; i < hi; i += 256)
    atomicAdd(&cnt[((unsigned)bucket[i]) >> 24], 1);
  __syncthreads();
  int node = w * WNODES + threadIdx.x;
  if (node < N) dinv[node] = rsqrtf((float)cnt[threadIdx.x] + 1.f);
}

// ---------------------------------------------------------------- fused aggregation: LDS fp32 accum + self-loop + bias + BN + ReLU
// block = window (256 nodes, 64KB acc); wave-per-edge, lane-per-feature.
// Output rows written once, dense, by a single block (no write amplification).
__global__ __launch_bounds__(1024) void k_agg2(const int* __restrict__ bucket,
                                               const int* __restrict__ woffs,
                                               const float* __restrict__ dinv,
                                               const h16* __restrict__ hin,
                                               const float* __restrict__ b,
                                               const float* __restrict__ g,
                                               const float* __restrict__ be,
                                               const float* __restrict__ m,
                                               const float* __restrict__ v,
                                               h16* __restrict__ hout, int N) {
  __shared__ float acc[WNODES * 64];
  float4* a4 = (float4*)acc;
  for (int i = threadIdx.x; i < WNODES * 16; i += 1024) a4[i] = make_float4(0.f, 0.f, 0.f, 0.f);
  __syncthreads();
  int w = blockIdx.x;
  int lane = threadIdx.x & 63, wv = threadIdx.x >> 6;
  int lo = woffs[w], hi = woffs[w + 1];
  int i = lo + wv;
  for (; i + 16 < hi; i += 32) {  // 2-edge unroll: row loads in flight together
    unsigned p0 = (unsigned)bucket[i], p1 = (unsigned)bucket[i + 16];
    int s0 = p0 & 0xFFFFFF, s1 = p1 & 0xFFFFFF;
    float w0 = dinv[s0], w1 = dinv[s1];
    float h0 = (float)hin[(long long)s0 * 64 + lane];
    float h1 = (float)hin[(long long)s1 * 64 + lane];
    atomicAdd(&acc[(p0 >> 24) * 64 + lane], w0 * h0);  // lane f -> bank f%32, 2-way free
    atomicAdd(&acc[(p1 >> 24) * 64 + lane], w1 * h1);
  }
  if (i < hi) {
    unsigned p0 = (unsigned)bucket[i];
    int s0 = p0 & 0xFFFFFF;
    atomicAdd(&acc[(p0 >> 24) * 64 + lane], dinv[s0] * (float)hin[(long long)s0 * 64 + lane]);
  }
  __syncthreads();
  float A = g[lane] * rsqrtf(v[lane] + EPSV);
  float B = be[lane] - m[lane] * A;
  float bb = b[lane];
  for (int n = wv; n < WNODES; n += 16) {
    int node = w * WNODES + n;
    if (node >= N) break;
    float di = dinv[node];
    float t = acc[n * 64 + lane] + di * (float)hin[(long long)node * 64 + lane];  // self-loop
    t = fmaf(di, t, bb);
    hout[(long long)node * 64 + lane] = (h16)fmaxf(fmaf(t, A, B), 0.f);
  }
}

// ---------------------------------------------------------------- GEMM1 (MFMA): h[N,64](f16) = x[N,128](f32) @ W[128,64](f32)
__global__ __launch_bounds__(256, 1) void k_gemm1(const float* __restrict__ x,
                                                  const float* __restrict__ W,
                                                  h16* __restrict__ h, int N) {
  int lane = threadIdx.x & 63;
  int wave = threadIdx.x >> 6;
  int q = lane >> 4, r16 = lane & 15;
  half8 bf[4][4];
#pragma unroll
  for (int t = 0; t < 4; ++t)
#pragma unroll
    for (int s = 0; s < 4; ++s) {
      const float* wp = W + (s * 32 + q * 8) * 64 + t * 16 + r16;
#pragma unroll
      for (int j = 0; j < 8; ++j) bf[t][s][j] = (h16)wp[j * 64];
    }
  long long base_row = (long long)blockIdx.x * 128 + wave * 32;
#pragma unroll
  for (int rt = 0; rt < 2; ++rt) {
    long long row0 = base_row + rt * 16;
    long long arow = row0 + r16;
    if (arow >= N) arow = N - 1;
    const float* xp = x + arow * 128 + q * 8;
    half8 af[4];
#pragma unroll
    for (int s = 0; s < 4; ++s) {
      float4 v0 = *(const float4*)(xp + s * 32);
      float4 v1 = *(const float4*)(xp + s * 32 + 4);
      af[s][0] = (h16)v0.x; af[s][1] = (h16)v0.y;
      af[s][2] = (h16)v0.z; af[s][3] = (h16)v0.w;
      af[s][4] = (h16)v1.x; af[s][5] = (h16)v1.y;
      af[s][6] = (h16)v1.z; af[s][7] = (h16)v1.w;
    }
    f32x4 acc[4] = {{0.f, 0.f, 0.f, 0.f}, {0.f, 0.f, 0.f, 0.f},
                    {0.f, 0.f, 0.f, 0.f}, {0.f, 0.f, 0.f, 0.f}};
#pragma unroll
    for (int s = 0; s < 4; ++s)
#pragma unroll
      for (int t = 0; t < 4; ++t)
        acc[t] = __builtin_amdgcn_mfma_f32_16x16x32_f16(af[s], bf[t][s], acc[t], 0, 0, 0);
#pragma unroll
    for (int t = 0; t < 4; ++t)
#pragma unroll
      for (int rr = 0; rr < 4; ++rr) {
        long long row = row0 + q * 4 + rr;
        if (row < N) h[row * 64 + t * 16 + r16] = (h16)acc[t][rr];
      }
  }
}

// ---------------------------------------------------------------- GEMM2 (MFMA): h[N,64](f16) = in[N,64](f16) @ W[64,64](f32)
__global__ __launch_bounds__(256, 1) void k_gemm2(const h16* __restrict__ xh,
                                                  const float* __restrict__ W,
                                                  h16* __restrict__ h, int N) {
  int lane = threadIdx.x & 63;
  int wave = threadIdx.x >> 6;
  int q = lane >> 4, r16 = lane & 15;
  half8 bf[4][2];
#pragma unroll
  for (int t = 0; t < 4; ++t)
#pragma unroll
    for (int s = 0; s < 2; ++s) {
      const float* wp = W + (s * 32 + q * 8) * 64 + t * 16 + r16;
#pragma unroll
      for (int j = 0; j < 8; ++j) bf[t][s][j] = (h16)wp[j * 64];
    }
  long long base_row = (long long)blockIdx.x * 128 + wave * 32;
#pragma unroll
  for (int rt = 0; rt < 2; ++rt) {
    long long row0 = base_row + rt * 16;
    long long arow = row0 + r16;
    if (arow >= N) arow = N - 1;
    half8 af[2];
#pragma unroll
    for (int s = 0; s < 2; ++s)
      af[s] = *(const half8*)(xh + arow * 64 + s * 32 + q * 8);
    f32x4 acc[4] = {{0.f, 0.f, 0.f, 0.f}, {0.f, 0.f, 0.f, 0.f},
                    {0.f, 0.f, 0.f, 0.f}, {0.f, 0.f, 0.f, 0.f}};
#pragma unroll
    for (int s = 0; s < 2; ++s)
#pragma unroll
      for (int t = 0; t < 4; ++t)
        acc[t] = __builtin_amdgcn_mfma_f32_16x16x32_f16(af[s], bf[t][s], acc[t], 0, 0, 0);
#pragma unroll
    for (int t = 0; t < 4; ++t)
#pragma unroll
      for (int rr = 0; rr < 4; ++rr) {
        long long row = row0 + q * 4 + rr;
        if (row < N) h[row * 64 + t * 16 + r16] = (h16)acc[t][rr];
      }
  }
}

// ---------------------------------------------------------------- MLP head + sigmoid (fp16 input, already BN+ReLU)
__global__ __launch_bounds__(256) void k_cls(const h16* __restrict__ h,
                                             const float* __restrict__ Wc1,
                                             const float* __restrict__ bc1,
                                             const float* __restrict__ Wc2,
                                             const float* __restrict__ bc2,
                                             float* __restrict__ out, int N) {
  __shared__ float sW1[64 * 32];
  __shared__ float sW2[32];
  __shared__ float sb1[32];
  for (int i = threadIdx.x; i < 64 * 32; i += blockDim.x) sW1[i] = Wc1[i];
  if (threadIdx.x < 32) {
    sW2[threadIdx.x] = Wc2[threadIdx.x];
    sb1[threadIdx.x] = bc1[threadIdx.x];
  }
  __syncthreads();
  int node = blockIdx.x * blockDim.x + threadIdx.x;
  if (node >= N) return;
  const uint4* hp = (const uint4*)(h + (long long)node * 64);
  float mid[32];
#pragma unroll
  for (int j = 0; j < 32; ++j) mid[j] = sb1[j];
#pragma unroll
  for (int j4 = 0; j4 < 8; ++j4) {
    uint4 qv = hp[j4];
    unsigned int pk[4] = {qv.x, qv.y, qv.z, qv.w};
#pragma unroll
    for (int c = 0; c < 4; ++c) {
      float f0 = h2f(pk[c] & 0xffffu);
      float f1 = h2f(pk[c] >> 16);
      int f = j4 * 8 + c * 2;
#pragma unroll
      for (int j = 0; j < 32; ++j) mid[j] = fmaf(f0, sW1[f * 32 + j], mid[j]);
#pragma unroll
      for (int j = 0; j < 32; ++j) mid[j] = fmaf(f1, sW1[(f + 1) * 32 + j], mid[j]);
    }
  }
  float o = bc2[0];
#pragma unroll
  for (int j = 0; j < 32; ++j) o = fmaf(fmaxf(mid[j], 0.f), sW2[j], o);
  out[node] = 1.f / (1.f + expf(-o));
}

// ---------------------------------------------------------------- launch
extern "C" void kernel_launch(void* const* d_in, const int* in_sizes, int n_in,
                              void* d_out, int out_size, void* d_ws, size_t ws_size,
                              hipStream_t stream) {
  const float* x  = (const float*)d_in[0];
  const int* ei   = (const int*)d_in[1];
  const float* W1 = (const float*)d_in[2];
  const float* b1 = (const float*)d_in[3];
  const float* g1 = (const float*)d_in[4];
  const float* be1 = (const float*)d_in[5];
  const float* m1 = (const float*)d_in[6];
  const float* v1 = (const float*)d_in[7];
  const float* W2 = (const float*)d_in[8];
  const float* b2 = (const float*)d_in[9];
  const float* g2 = (const float*)d_in[10];
  const float* be2 = (const float*)d_in[11];
  const float* m2 = (const float*)d_in[12];
  const float* v2 = (const float*)d_in[13];
  const float* Wc1 = (const float*)d_in[14];
  const float* bc1 = (const float*)d_in[15];
  const float* Wc2 = (const float*)d_in[16];
  const float* bc2 = (const float*)d_in[17];
  float* out = (float*)d_out;

  int N = in_sizes[0] / 128;
  int E = in_sizes[1] / 2;
  int Npad = ((N + 63) / 64) * 64;
  int nw = (N + WNODES - 1) / WNODES;  // windows (<=512 for N<=131072)

  char* ws = (char*)d_ws;
  h16*   bufA   = (h16*)ws;                              // [N*64] fp16
  h16*   bufB   = bufA + (long long)N * 64;              // [N*64] fp16
  int*   bucket = (int*)(bufB + (long long)N * 64);      // [E]
  int*   cnt512 = bucket + E;                            // [SBLK*nw] -> becomes base512
  int*   woffs  = cnt512 + SBLK * nw;                    // [nw+1]
  float* dinv   = (float*)(woffs + nw + 64);             // [Npad]
  size_t need = (size_t)((char*)(dinv + Npad) - (char*)d_ws);
  if (need > ws_size) return;  // fail loudly rather than corrupt

  // ---- graph preprocessing: window-bucketed edges (no CSR, no global atomics) ----
  k_cnt<<<SBLK, 256, 0, stream>>>(ei, cnt512, E, nw);
  k_scan2<<<1, 512, 0, stream>>>(cnt512, woffs, E, nw);
  k_append<<<SBLK, 256, 0, stream>>>(ei, cnt512, bucket, E, nw);
  k_degw<<<nw, 256, 0, stream>>>(bucket, woffs, dinv, N);

  // ---- layer 1 ----
  k_gemm1<<<(N + 127) / 128, 256, 0, stream>>>(x, W1, bufA, N);
  k_agg2<<<nw, 1024, 0, stream>>>(bucket, woffs, dinv, bufA,
                                  b1, g1, be1, m1, v1, bufB, N);
  // ---- layer 2 ----
  k_gemm2<<<(N + 127) / 128, 256, 0, stream>>>(bufB, W2, bufA, N);
  k_agg2<<<nw, 1024, 0, stream>>>(bucket, woffs, dinv, bufA,
                                  b2, g2, be2, m2, v2, bufB, N);
  // ---- classifier head ----
  k_cls<<<(N + 255) / 256, 256, 0, stream>>>(bufB, Wc1, bc1, Wc2, bc2, out, N);
}

// Round 10
// 372.341 us; speedup vs baseline: 4.3504x; 4.3504x over previous
//
#include <hip/hip_runtime.h>
#include <math.h>

#define EPSV 1e-5f
#define SBLK 512      // edge slices for count/append
#define WNODES 256    // nodes per window

typedef _Float16 h16;
typedef _Float16 half8 __attribute__((ext_vector_type(8)));
typedef float f32x4 __attribute__((ext_vector_type(4)));

static __device__ __forceinline__ float h2f(unsigned int u16) {
  unsigned short s = (unsigned short)u16;
  h16 h;
  __builtin_memcpy(&h, &s, 2);
  return (float)h;
}

// ---------------------------------------------------------------- per-(slice,window) edge counts
__global__ __launch_bounds__(256) void k_cnt(const int* __restrict__ ei,
                                             int* __restrict__ cnt512, int E, int nw) {
  __shared__ int hist[512];
  int s = blockIdx.x;
  for (int i = threadIdx.x; i < nw; i += 256) hist[i] = 0;
  __syncthreads();
  long long elo = (long long)s * E / SBLK, ehi = (long long)(s + 1) * E / SBLK;
  for (long long i = elo + threadIdx.x; i < ehi; i += 256)
    atomicAdd(&hist[ei[E + i] >> 8], 1);          // int LDS atomic (native ds_add)
  __syncthreads();
  for (int i = threadIdx.x; i < nw; i += 256) cnt512[s * nw + i] = hist[i];
}

// ---------------------------------------------------------------- scan: window bases + per-(slice,window) bases (in-place)
__global__ __launch_bounds__(512) void k_scan2(int* __restrict__ cnt512,
                                               int* __restrict__ woffs, int E, int nw) {
  int w = threadIdx.x;
  int tot = 0;
  if (w < nw) {
#pragma unroll 8
    for (int s = 0; s < SBLK; ++s) tot += cnt512[s * nw + w];
  }
  __shared__ int sh[512];
  sh[w] = tot;
  __syncthreads();
  for (int off = 1; off < 512; off <<= 1) {
    int u = (w >= off) ? sh[w - off] : 0;
    __syncthreads();
    sh[w] += u;
    __syncthreads();
  }
  int base = sh[w] - tot;
  if (w < nw) {
    woffs[w] = base;
    int run = base;
    for (int s = 0; s < SBLK; ++s) {
      int c = cnt512[s * nw + w];
      cnt512[s * nw + w] = run;
      run += c;
    }
  }
  if (w == 0) woffs[nw] = E;
}

// ---------------------------------------------------------------- append: bucket[pos] = src | (dst_lo<<24), window-grouped
__global__ __launch_bounds__(256) void k_append(const int* __restrict__ ei,
                                                const int* __restrict__ base512,
                                                int* __restrict__ bucket, int E, int nw) {
  __shared__ int cur[512];
  int s = blockIdx.x;
  for (int i = threadIdx.x; i < nw; i += 256) cur[i] = base512[s * nw + i];
  __syncthreads();
  long long elo = (long long)s * E / SBLK, ehi = (long long)(s + 1) * E / SBLK;
  for (long long i = elo + threadIdx.x; i < ehi; i += 256) {
    int d = ei[E + i];
    int src = ei[i];
    int pos = atomicAdd(&cur[d >> 8], 1);          // int LDS atomic
    bucket[pos] = src | ((d & 255) << 24);
  }
}

// ---------------------------------------------------------------- window counting-sort -> node-grouped csr + offs + dinv
// One block per window; segment (~16KB) read/written L2-local by a single block.
// Int LDS atomics only (native ds_add) — NO fp LDS atomics.
__global__ __launch_bounds__(256) void k_sortw(const int* __restrict__ bucket,
                                               const int* __restrict__ woffs,
                                               int* __restrict__ csr,
                                               int* __restrict__ offs,
                                               float* __restrict__ dinv, int N, int E) {
  __shared__ int cnt[WNODES];
  __shared__ int sc[WNODES];
  __shared__ int cur[WNODES];
  int w = blockIdx.x, t = threadIdx.x;
  int lo = woffs[w], hi = woffs[w + 1];
  cnt[t] = 0;
  __syncthreads();
  for (int i = lo + t; i < hi; i += 256)
    atomicAdd(&cnt[((unsigned)bucket[i]) >> 24], 1);
  __syncthreads();
  int c = cnt[t];
  sc[t] = c;
  __syncthreads();
  for (int off = 1; off < 256; off <<= 1) {       // Hillis-Steele inclusive scan
    int u = (t >= off) ? sc[t - off] : 0;
    __syncthreads();
    sc[t] += u;
    __syncthreads();
  }
  int excl = sc[t] - c;                            // exclusive prefix within window
  int node = w * WNODES + t;
  if (node < N) {
    offs[node] = lo + excl;
    dinv[node] = rsqrtf((float)c + 1.f);
  }
  cur[t] = excl;
  if (w == 0 && t == 0) offs[N] = E;
  __syncthreads();
  for (int i = lo + t; i < hi; i += 256) {
    unsigned p = (unsigned)bucket[i];
    int pos = atomicAdd(&cur[p >> 24], 1);         // int LDS cursor
    csr[lo + pos] = (int)(p & 0xFFFFFFu);
  }
}

// ---------------------------------------------------------------- GEMM1 (MFMA): h[N,64](f16) = x[N,128](f32) @ W[128,64](f32)
__global__ __launch_bounds__(256, 1) void k_gemm1(const float* __restrict__ x,
                                                  const float* __restrict__ W,
                                                  h16* __restrict__ h, int N) {
  int lane = threadIdx.x & 63;
  int wave = threadIdx.x >> 6;
  int q = lane >> 4, r16 = lane & 15;
  half8 bf[4][4];
#pragma unroll
  for (int t = 0; t < 4; ++t)
#pragma unroll
    for (int s = 0; s < 4; ++s) {
      const float* wp = W + (s * 32 + q * 8) * 64 + t * 16 + r16;
#pragma unroll
      for (int j = 0; j < 8; ++j) bf[t][s][j] = (h16)wp[j * 64];
    }
  long long base_row = (long long)blockIdx.x * 128 + wave * 32;
#pragma unroll
  for (int rt = 0; rt < 2; ++rt) {
    long long row0 = base_row + rt * 16;
    long long arow = row0 + r16;
    if (arow >= N) arow = N - 1;
    const float* xp = x + arow * 128 + q * 8;
    half8 af[4];
#pragma unroll
    for (int s = 0; s < 4; ++s) {
      float4 v0 = *(const float4*)(xp + s * 32);
      float4 v1 = *(const float4*)(xp + s * 32 + 4);
      af[s][0] = (h16)v0.x; af[s][1] = (h16)v0.y;
      af[s][2] = (h16)v0.z; af[s][3] = (h16)v0.w;
      af[s][4] = (h16)v1.x; af[s][5] = (h16)v1.y;
      af[s][6] = (h16)v1.z; af[s][7] = (h16)v1.w;
    }
    f32x4 acc[4] = {{0.f, 0.f, 0.f, 0.f}, {0.f, 0.f, 0.f, 0.f},
                    {0.f, 0.f, 0.f, 0.f}, {0.f, 0.f, 0.f, 0.f}};
#pragma unroll
    for (int s = 0; s < 4; ++s)
#pragma unroll
      for (int t = 0; t < 4; ++t)
        acc[t] = __builtin_amdgcn_mfma_f32_16x16x32_f16(af[s], bf[t][s], acc[t], 0, 0, 0);
#pragma unroll
    for (int t = 0; t < 4; ++t)
#pragma unroll
      for (int rr = 0; rr < 4; ++rr) {
        long long row = row0 + q * 4 + rr;
        if (row < N) h[row * 64 + t * 16 + r16] = (h16)acc[t][rr];
      }
  }
}

// ---------------------------------------------------------------- GEMM2 (MFMA): h[N,64](f16) = in[N,64](f16) @ W[64,64](f32)
__global__ __launch_bounds__(256, 1) void k_gemm2(const h16* __restrict__ xh,
                                                  const float* __restrict__ W,
                                                  h16* __restrict__ h, int N) {
  int lane = threadIdx.x & 63;
  int wave = threadIdx.x >> 6;
  int q = lane >> 4, r16 = lane & 15;
  half8 bf[4][2];
#pragma unroll
  for (int t = 0; t < 4; ++t)
#pragma unroll
    for (int s = 0; s < 2; ++s) {
      const float* wp = W + (s * 32 + q * 8) * 64 + t * 16 + r16;
#pragma unroll
      for (int j = 0; j < 8; ++j) bf[t][s][j] = (h16)wp[j * 64];
    }
  long long base_row = (long long)blockIdx.x * 128 + wave * 32;
#pragma unroll
  for (int rt = 0; rt < 2; ++rt) {
    long long row0 = base_row + rt * 16;
    long long arow = row0 + r16;
    if (arow >= N) arow = N - 1;
    half8 af[2];
#pragma unroll
    for (int s = 0; s < 2; ++s)
      af[s] = *(const half8*)(xh + arow * 64 + s * 32 + q * 8);
    f32x4 acc[4] = {{0.f, 0.f, 0.f, 0.f}, {0.f, 0.f, 0.f, 0.f},
                    {0.f, 0.f, 0.f, 0.f}, {0.f, 0.f, 0.f, 0.f}};
#pragma unroll
    for (int s = 0; s < 2; ++s)
#pragma unroll
      for (int t = 0; t < 4; ++t)
        acc[t] = __builtin_amdgcn_mfma_f32_16x16x32_f16(af[s], bf[t][s], acc[t], 0, 0, 0);
#pragma unroll
    for (int t = 0; t < 4; ++t)
#pragma unroll
      for (int rr = 0; rr < 4; ++rr) {
        long long row = row0 + q * 4 + rr;
        if (row < N) h[row * 64 + t * 16 + r16] = (h16)acc[t][rr];
      }
  }
}

// ---------------------------------------------------------------- CSR gather + self-loop + bias + BN + ReLU (fused, fp16 h)
// wave per node, lane = feature; register accumulate (proven r4-r7).
__global__ __launch_bounds__(256) void k_gath(const int* __restrict__ csr,
                                              const int* __restrict__ offs,
                                              const float* __restrict__ dinv,
                                              const h16* __restrict__ hin,
                                              const float* __restrict__ b,
                                              const float* __restrict__ g,
                                              const float* __restrict__ be,
                                              const float* __restrict__ m,
                                              const float* __restrict__ v,
                                              h16* __restrict__ hout, int N) {
  int lane = threadIdx.x & 63;
  int node = (int)(((long long)blockIdx.x * blockDim.x + threadIdx.x) >> 6);
  if (node >= N) return;
  node = __builtin_amdgcn_readfirstlane(node);
  int beg = offs[node], end = offs[node + 1];
  float acc = 0.f;
  int j = beg;
  for (; j + 4 <= end; j += 4) {  // 4 independent row loads in flight
    int s0 = csr[j], s1 = csr[j + 1], s2 = csr[j + 2], s3 = csr[j + 3];
    float w0 = dinv[s0], w1 = dinv[s1], w2 = dinv[s2], w3 = dinv[s3];
    float h0 = (float)hin[(long long)s0 * 64 + lane];
    float h1 = (float)hin[(long long)s1 * 64 + lane];
    float h2 = (float)hin[(long long)s2 * 64 + lane];
    float h3 = (float)hin[(long long)s3 * 64 + lane];
    acc = fmaf(w0, h0, acc);
    acc = fmaf(w1, h1, acc);
    acc = fmaf(w2, h2, acc);
    acc = fmaf(w3, h3, acc);
  }
  for (; j < end; ++j) {
    int s = csr[j];
    acc = fmaf(dinv[s], (float)hin[(long long)s * 64 + lane], acc);
  }
  float di = dinv[node];
  acc = fmaf(di, (float)hin[(long long)node * 64 + lane], acc);  // self-loop
  acc = fmaf(di, acc, b[lane]);                                  // scale + bias
  float A = g[lane] * rsqrtf(v[lane] + EPSV);
  float B = be[lane] - m[lane] * A;
  hout[(long long)node * 64 + lane] = (h16)fmaxf(fmaf(acc, A, B), 0.f);
}

// ---------------------------------------------------------------- MLP head + sigmoid (fp16 input, already BN+ReLU)
__global__ __launch_bounds__(256) void k_cls(const h16* __restrict__ h,
                                             const float* __restrict__ Wc1,
                                             const float* __restrict__ bc1,
                                             const float* __restrict__ Wc2,
                                             const float* __restrict__ bc2,
                                             float* __restrict__ out, int N) {
  __shared__ float sW1[64 * 32];
  __shared__ float sW2[32];
  __shared__ float sb1[32];
  for (int i = threadIdx.x; i < 64 * 32; i += blockDim.x) sW1[i] = Wc1[i];
  if (threadIdx.x < 32) {
    sW2[threadIdx.x] = Wc2[threadIdx.x];
    sb1[threadIdx.x] = bc1[threadIdx.x];
  }
  __syncthreads();
  int node = blockIdx.x * blockDim.x + threadIdx.x;
  if (node >= N) return;
  const uint4* hp = (const uint4*)(h + (long long)node * 64);
  float mid[32];
#pragma unroll
  for (int j = 0; j < 32; ++j) mid[j] = sb1[j];
#pragma unroll
  for (int j4 = 0; j4 < 8; ++j4) {
    uint4 qv = hp[j4];
    unsigned int pk[4] = {qv.x, qv.y, qv.z, qv.w};
#pragma unroll
    for (int c = 0; c < 4; ++c) {
      float f0 = h2f(pk[c] & 0xffffu);
      float f1 = h2f(pk[c] >> 16);
      int f = j4 * 8 + c * 2;
#pragma unroll
      for (int j = 0; j < 32; ++j) mid[j] = fmaf(f0, sW1[f * 32 + j], mid[j]);
#pragma unroll
      for (int j = 0; j < 32; ++j) mid[j] = fmaf(f1, sW1[(f + 1) * 32 + j], mid[j]);
    }
  }
  float o = bc2[0];
#pragma unroll
  for (int j = 0; j < 32; ++j) o = fmaf(fmaxf(mid[j], 0.f), sW2[j], o);
  out[node] = 1.f / (1.f + expf(-o));
}

// ---------------------------------------------------------------- launch
extern "C" void kernel_launch(void* const* d_in, const int* in_sizes, int n_in,
                              void* d_out, int out_size, void* d_ws, size_t ws_size,
                              hipStream_t stream) {
  const float* x  = (const float*)d_in[0];
  const int* ei   = (const int*)d_in[1];
  const float* W1 = (const float*)d_in[2];
  const float* b1 = (const float*)d_in[3];
  const float* g1 = (const float*)d_in[4];
  const float* be1 = (const float*)d_in[5];
  const float* m1 = (const float*)d_in[6];
  const float* v1 = (const float*)d_in[7];
  const float* W2 = (const float*)d_in[8];
  const float* b2 = (const float*)d_in[9];
  const float* g2 = (const float*)d_in[10];
  const float* be2 = (const float*)d_in[11];
  const float* m2 = (const float*)d_in[12];
  const float* v2 = (const float*)d_in[13];
  const float* Wc1 = (const float*)d_in[14];
  const float* bc1 = (const float*)d_in[15];
  const float* Wc2 = (const float*)d_in[16];
  const float* bc2 = (const float*)d_in[17];
  float* out = (float*)d_out;

  int N = in_sizes[0] / 128;
  int E = in_sizes[1] / 2;
  int Npad = ((N + 63) / 64) * 64;
  int nw = (N + WNODES - 1) / WNODES;  // windows (<=512 for N<=131072)

  char* ws = (char*)d_ws;
  h16*   bufA   = (h16*)ws;                              // [N*64] fp16
  h16*   bufB   = bufA + (long long)N * 64;              // [N*64] fp16
  int*   bucket = (int*)(bufB + (long long)N * 64);      // [E]
  int*   csr    = bucket + E;                            // [E]
  int*   cnt512 = csr + E;                               // [SBLK*nw]
  int*   woffs  = cnt512 + SBLK * nw;                    // [nw+1]
  int*   offs   = woffs + nw + 64;                       // [N+64]
  float* dinv   = (float*)(offs + Npad + 64);            // [Npad]
  size_t need = (size_t)((char*)(dinv + Npad) - (char*)d_ws);
  if (need > ws_size) return;  // fail loudly rather than corrupt

  // ---- graph preprocessing: window bucket + window-local counting sort ----
  k_cnt<<<SBLK, 256, 0, stream>>>(ei, cnt512, E, nw);
  k_scan2<<<1, 512, 0, stream>>>(cnt512, woffs, E, nw);
  k_append<<<SBLK, 256, 0, stream>>>(ei, cnt512, bucket, E, nw);
  k_sortw<<<nw, 256, 0, stream>>>(bucket, woffs, csr, offs, dinv, N, E);

  // ---- layer 1 ----
  k_gemm1<<<(N + 127) / 128, 256, 0, stream>>>(x, W1, bufA, N);
  k_gath<<<(N * 64 + 255) / 256, 256, 0, stream>>>(csr, offs, dinv, bufA,
                                                   b1, g1, be1, m1, v1, bufB, N);
  // ---- layer 2 ----
  k_gemm2<<<(N + 127) / 128, 256, 0, stream>>>(bufB, W2, bufA, N);
  k_gath<<<(N * 64 + 255) / 256, 256, 0, stream>>>(csr, offs, dinv, bufA,
                                                   b2, g2, be2, m2, v2, bufB, N);
  // ---- classifier head ----
  k_cls<<<(N + 255) / 256, 256, 0, stream>>>(bufB, Wc1, bc1, Wc2, bc2, out, N);
}

// Round 12
// 320.744 us; speedup vs baseline: 5.0503x; 1.1609x over previous
//
#include <hip/hip_runtime.h>
#include <math.h>

#define EPSV 1e-5f
#define SBLK 512      // edge slices for count/append
#define WNODES 256    // nodes per window

typedef _Float16 h16;
typedef _Float16 half8 __attribute__((ext_vector_type(8)));
typedef float f32x4 __attribute__((ext_vector_type(4)));

static __device__ __forceinline__ float h2f(unsigned int u16) {
  unsigned short s = (unsigned short)u16;
  h16 h;
  __builtin_memcpy(&h, &s, 2);
  return (float)h;
}

// ---------------------------------------------------------------- per-(slice,window) edge counts
__global__ __launch_bounds__(256) void k_cnt(const int* __restrict__ ei,
                                             int* __restrict__ cnt512, int E, int nw) {
  __shared__ int hist[512];
  int s = blockIdx.x;
  for (int i = threadIdx.x; i < nw; i += 256) hist[i] = 0;
  __syncthreads();
  long long elo = (long long)s * E / SBLK, ehi = (long long)(s + 1) * E / SBLK;
  for (long long i = elo + threadIdx.x; i < ehi; i += 256)
    atomicAdd(&hist[ei[E + i] >> 8], 1);          // int LDS atomic (native ds_add)
  __syncthreads();
  for (int i = threadIdx.x; i < nw; i += 256) cnt512[s * nw + i] = hist[i];
}

// ---------------------------------------------------------------- scanA: per-window scan over slices (block per window)
__global__ __launch_bounds__(512) void k_scanA(int* __restrict__ cnt512,
                                               int* __restrict__ wtot, int nw) {
  int w = blockIdx.x, t = threadIdx.x;
  int c = cnt512[t * nw + w];
  __shared__ int sc[512];
  sc[t] = c;
  __syncthreads();
  for (int off = 1; off < 512; off <<= 1) {
    int u = (t >= off) ? sc[t - off] : 0;
    __syncthreads();
    sc[t] += u;
    __syncthreads();
  }
  cnt512[t * nw + w] = sc[t] - c;                 // window-local exclusive base
  if (t == 511) wtot[w] = sc[511];
}

// ---------------------------------------------------------------- scanB: exclusive scan of window totals (1 tiny block)
__global__ __launch_bounds__(512) void k_scanB(const int* __restrict__ wtot,
                                               int* __restrict__ woffs, int nw, int E) {
  int t = threadIdx.x;
  int c = (t < nw) ? wtot[t] : 0;
  __shared__ int sc[512];
  sc[t] = c;
  __syncthreads();
  for (int off = 1; off < 512; off <<= 1) {
    int u = (t >= off) ? sc[t - off] : 0;
    __syncthreads();
    sc[t] += u;
    __syncthreads();
  }
  if (t < nw) woffs[t] = sc[t] - c;
  if (t == 0) woffs[nw] = E;
}

// ---------------------------------------------------------------- append: bucket[pos] = src | (dst_lo<<24), window-grouped
__global__ __launch_bounds__(256) void k_append(const int* __restrict__ ei,
                                                const int* __restrict__ base512,
                                                const int* __restrict__ woffs,
                                                int* __restrict__ bucket, int E, int nw) {
  __shared__ int cur[512];
  int s = blockIdx.x;
  for (int i = threadIdx.x; i < nw; i += 256)
    cur[i] = base512[s * nw + i] + woffs[i];
  __syncthreads();
  long long elo = (long long)s * E / SBLK, ehi = (long long)(s + 1) * E / SBLK;
  for (long long i = elo + threadIdx.x; i < ehi; i += 256) {
    int d = ei[E + i];
    int src = ei[i];
    int pos = atomicAdd(&cur[d >> 8], 1);          // int LDS atomic
    bucket[pos] = src | ((d & 255) << 24);
  }
}

// ---------------------------------------------------------------- window counting-sort -> node-grouped csr + offs + dinv
__global__ __launch_bounds__(256) void k_sortw(const int* __restrict__ bucket,
                                               const int* __restrict__ woffs,
                                               int* __restrict__ csr,
                                               int* __restrict__ offs,
                                               float* __restrict__ dinv, int N, int E) {
  __shared__ int cnt[WNODES];
  __shared__ int sc[WNODES];
  __shared__ int cur[WNODES];
  int w = blockIdx.x, t = threadIdx.x;
  int lo = woffs[w], hi = woffs[w + 1];
  cnt[t] = 0;
  __syncthreads();
  for (int i = lo + t; i < hi; i += 256)
    atomicAdd(&cnt[((unsigned)bucket[i]) >> 24], 1);
  __syncthreads();
  int c = cnt[t];
  sc[t] = c;
  __syncthreads();
  for (int off = 1; off < 256; off <<= 1) {
    int u = (t >= off) ? sc[t - off] : 0;
    __syncthreads();
    sc[t] += u;
    __syncthreads();
  }
  int excl = sc[t] - c;
  int node = w * WNODES + t;
  if (node < N) {
    offs[node] = lo + excl;
    dinv[node] = rsqrtf((float)c + 1.f);
  }
  cur[t] = excl;
  if (w == 0 && t == 0) offs[N] = E;
  __syncthreads();
  for (int i = lo + t; i < hi; i += 256) {
    unsigned p = (unsigned)bucket[i];
    int pos = atomicAdd(&cur[p >> 24], 1);
    csr[lo + pos] = (int)(p & 0xFFFFFFu);
  }
}

// ---------------------------------------------------------------- GEMM1 (MFMA): h[N,64](f16) = x[N,128](f32) @ W[128,64](f32)
__global__ __launch_bounds__(256, 1) void k_gemm1(const float* __restrict__ x,
                                                  const float* __restrict__ W,
                                                  h16* __restrict__ h, int N) {
  int lane = threadIdx.x & 63;
  int wave = threadIdx.x >> 6;
  int q = lane >> 4, r16 = lane & 15;
  half8 bf[4][4];
#pragma unroll
  for (int t = 0; t < 4; ++t)
#pragma unroll
    for (int s = 0; s < 4; ++s) {
      const float* wp = W + (s * 32 + q * 8) * 64 + t * 16 + r16;
#pragma unroll
      for (int j = 0; j < 8; ++j) bf[t][s][j] = (h16)wp[j * 64];
    }
  long long base_row = (long long)blockIdx.x * 128 + wave * 32;
#pragma unroll
  for (int rt = 0; rt < 2; ++rt) {
    long long row0 = base_row + rt * 16;
    long long arow = row0 + r16;
    if (arow >= N) arow = N - 1;
    const float* xp = x + arow * 128 + q * 8;
    half8 af[4];
#pragma unroll
    for (int s = 0; s < 4; ++s) {
      float4 v0 = *(const float4*)(xp + s * 32);
      float4 v1 = *(const float4*)(xp + s * 32 + 4);
      af[s][0] = (h16)v0.x; af[s][1] = (h16)v0.y;
      af[s][2] = (h16)v0.z; af[s][3] = (h16)v0.w;
      af[s][4] = (h16)v1.x; af[s][5] = (h16)v1.y;
      af[s][6] = (h16)v1.z; af[s][7] = (h16)v1.w;
    }
    f32x4 acc[4] = {{0.f, 0.f, 0.f, 0.f}, {0.f, 0.f, 0.f, 0.f},
                    {0.f, 0.f, 0.f, 0.f}, {0.f, 0.f, 0.f, 0.f}};
#pragma unroll
    for (int s = 0; s < 4; ++s)
#pragma unroll
      for (int t = 0; t < 4; ++t)
        acc[t] = __builtin_amdgcn_mfma_f32_16x16x32_f16(af[s], bf[t][s], acc[t], 0, 0, 0);
#pragma unroll
    for (int t = 0; t < 4; ++t)
#pragma unroll
      for (int rr = 0; rr < 4; ++rr) {
        long long row = row0 + q * 4 + rr;
        if (row < N) h[row * 64 + t * 16 + r16] = (h16)acc[t][rr];
      }
  }
}

// ---------------------------------------------------------------- GEMM2 (MFMA): h[N,64](f16) = in[N,64](f16) @ W[64,64](f32)
__global__ __launch_bounds__(256, 1) void k_gemm2(const h16* __restrict__ xh,
                                                  const float* __restrict__ W,
                                                  h16* __restrict__ h, int N) {
  int lane = threadIdx.x & 63;
  int wave = threadIdx.x >> 6;
  int q = lane >> 4, r16 = lane & 15;
  half8 bf[4][2];
#pragma unroll
  for (int t = 0; t < 4; ++t)
#pragma unroll
    for (int s = 0; s < 2; ++s) {
      const float* wp = W + (s * 32 + q * 8) * 64 + t * 16 + r16;
#pragma unroll
      for (int j = 0; j < 8; ++j) bf[t][s][j] = (h16)wp[j * 64];
    }
  long long base_row = (long long)blockIdx.x * 128 + wave * 32;
#pragma unroll
  for (int rt = 0; rt < 2; ++rt) {
    long long row0 = base_row + rt * 16;
    long long arow = row0 + r16;
    if (arow >= N) arow = N - 1;
    half8 af[2];
#pragma unroll
    for (int s = 0; s < 2; ++s)
      af[s] = *(const half8*)(xh + arow * 64 + s * 32 + q * 8);
    f32x4 acc[4] = {{0.f, 0.f, 0.f, 0.f}, {0.f, 0.f, 0.f, 0.f},
                    {0.f, 0.f, 0.f, 0.f}, {0.f, 0.f, 0.f, 0.f}};
#pragma unroll
    for (int s = 0; s < 2; ++s)
#pragma unroll
      for (int t = 0; t < 4; ++t)
        acc[t] = __builtin_amdgcn_mfma_f32_16x16x32_f16(af[s], bf[t][s], acc[t], 0, 0, 0);
#pragma unroll
    for (int t = 0; t < 4; ++t)
#pragma unroll
      for (int rr = 0; rr < 4; ++rr) {
        long long row = row0 + q * 4 + rr;
        if (row < N) h[row * 64 + t * 16 + r16] = (h16)acc[t][rr];
      }
  }
}

// ---------------------------------------------------------------- CSR gather + self-loop + bias + BN + ReLU (fused, fp16 h)
// wave per node, lane = feature; 8 independent row loads in flight (latency depth).
__global__ __launch_bounds__(256) void k_gath(const int* __restrict__ csr,
                                              const int* __restrict__ offs,
                                              const float* __restrict__ dinv,
                                              const h16* __restrict__ hin,
                                              const float* __restrict__ b,
                                              const float* __restrict__ g,
                                              const float* __restrict__ be,
                                              const float* __restrict__ m,
                                              const float* __restrict__ v,
                                              h16* __restrict__ hout, int N) {
  int lane = threadIdx.x & 63;
  int node = (int)(((long long)blockIdx.x * blockDim.x + threadIdx.x) >> 6);
  if (node >= N) return;
  node = __builtin_amdgcn_readfirstlane(node);
  int beg = offs[node], end = offs[node + 1];
  float acc = 0.f;
  int j = beg;
  for (; j + 8 <= end; j += 8) {  // 8 independent row loads in flight
    int s0 = csr[j],     s1 = csr[j + 1], s2 = csr[j + 2], s3 = csr[j + 3];
    int s4 = csr[j + 4], s5 = csr[j + 5], s6 = csr[j + 6], s7 = csr[j + 7];
    float w0 = dinv[s0], w1 = dinv[s1], w2 = dinv[s2], w3 = dinv[s3];
    float w4 = dinv[s4], w5 = dinv[s5], w6 = dinv[s6], w7 = dinv[s7];
    float h0 = (float)hin[(long long)s0 * 64 + lane];
    float h1 = (float)hin[(long long)s1 * 64 + lane];
    float h2 = (float)hin[(long long)s2 * 64 + lane];
    float h3 = (float)hin[(long long)s3 * 64 + lane];
    float h4 = (float)hin[(long long)s4 * 64 + lane];
    float h5 = (float)hin[(long long)s5 * 64 + lane];
    float h6 = (float)hin[(long long)s6 * 64 + lane];
    float h7 = (float)hin[(long long)s7 * 64 + lane];
    acc = fmaf(w0, h0, acc);
    acc = fmaf(w1, h1, acc);
    acc = fmaf(w2, h2, acc);
    acc = fmaf(w3, h3, acc);
    acc = fmaf(w4, h4, acc);
    acc = fmaf(w5, h5, acc);
    acc = fmaf(w6, h6, acc);
    acc = fmaf(w7, h7, acc);
  }
  for (; j < end; ++j) {
    int s = csr[j];
    acc = fmaf(dinv[s], (float)hin[(long long)s * 64 + lane], acc);
  }
  float di = dinv[node];
  acc = fmaf(di, (float)hin[(long long)node * 64 + lane], acc);  // self-loop
  acc = fmaf(di, acc, b[lane]);                                  // scale + bias
  float A = g[lane] * rsqrtf(v[lane] + EPSV);
  float B = be[lane] - m[lane] * A;
  hout[(long long)node * 64 + lane] = (h16)fmaxf(fmaf(acc, A, B), 0.f);
}

// ---------------------------------------------------------------- MLP head + sigmoid (fp16 input, already BN+ReLU)
__global__ __launch_bounds__(256) void k_cls(const h16* __restrict__ h,
                                             const float* __restrict__ Wc1,
                                             const float* __restrict__ bc1,
                                             const float* __restrict__ Wc2,
                                             const float* __restrict__ bc2,
                                             float* __restrict__ out, int N) {
  __shared__ float sW1[64 * 32];
  __shared__ float sW2[32];
  __shared__ float sb1[32];
  for (int i = threadIdx.x; i < 64 * 32; i += blockDim.x) sW1[i] = Wc1[i];
  if (threadIdx.x < 32) {
    sW2[threadIdx.x] = Wc2[threadIdx.x];
    sb1[threadIdx.x] = bc1[threadIdx.x];
  }
  __syncthreads();
  int node = blockIdx.x * blockDim.x + threadIdx.x;
  if (node >= N) return;
  const uint4* hp = (const uint4*)(h + (long long)node * 64);
  float mid[32];
#pragma unroll
  for (int j = 0; j < 32; ++j) mid[j] = sb1[j];
#pragma unroll
  for (int j4 = 0; j4 < 8; ++j4) {
    uint4 qv = hp[j4];
    unsigned int pk[4] = {qv.x, qv.y, qv.z, qv.w};
#pragma unroll
    for (int c = 0; c < 4; ++c) {
      float f0 = h2f(pk[c] & 0xffffu);
      float f1 = h2f(pk[c] >> 16);
      int f = j4 * 8 + c * 2;
#pragma unroll
      for (int j = 0; j < 32; ++j) mid[j] = fmaf(f0, sW1[f * 32 + j], mid[j]);
#pragma unroll
      for (int j = 0; j < 32; ++j) mid[j] = fmaf(f1, sW1[(f + 1) * 32 + j], mid[j]);
    }
  }
  float o = bc2[0];
#pragma unroll
  for (int j = 0; j < 32; ++j) o = fmaf(fmaxf(mid[j], 0.f), sW2[j], o);
  out[node] = 1.f / (1.f + expf(-o));
}

// ---------------------------------------------------------------- launch
extern "C" void kernel_launch(void* const* d_in, const int* in_sizes, int n_in,
                              void* d_out, int out_size, void* d_ws, size_t ws_size,
                              hipStream_t stream) {
  const float* x  = (const float*)d_in[0];
  const int* ei   = (const int*)d_in[1];
  const float* W1 = (const float*)d_in[2];
  const float* b1 = (const float*)d_in[3];
  const float* g1 = (const float*)d_in[4];
  const float* be1 = (const float*)d_in[5];
  const float* m1 = (const float*)d_in[6];
  const float* v1 = (const float*)d_in[7];
  const float* W2 = (const float*)d_in[8];
  const float* b2 = (const float*)d_in[9];
  const float* g2 = (const float*)d_in[10];
  const float* be2 = (const float*)d_in[11];
  const float* m2 = (const float*)d_in[12];
  const float* v2 = (const float*)d_in[13];
  const float* Wc1 = (const float*)d_in[14];
  const float* bc1 = (const float*)d_in[15];
  const float* Wc2 = (const float*)d_in[16];
  const float* bc2 = (const float*)d_in[17];
  float* out = (float*)d_out;

  int N = in_sizes[0] / 128;
  int E = in_sizes[1] / 2;
  int Npad = ((N + 63) / 64) * 64;
  int nw = (N + WNODES - 1) / WNODES;  // windows (<=512 for N<=131072)

  char* ws = (char*)d_ws;
  h16*   bufA   = (h16*)ws;                              // [N*64] fp16
  h16*   bufB   = bufA + (long long)N * 64;              // [N*64] fp16
  int*   bucket = (int*)(bufB + (long long)N * 64);      // [E]
  int*   csr    = bucket + E;                            // [E]
  int*   cnt512 = csr + E;                               // [SBLK*nw]
  int*   wtot   = cnt512 + SBLK * nw;                    // [512]
  int*   woffs  = wtot + 512;                            // [nw+1]
  int*   offs   = woffs + nw + 64;                       // [N+64]
  float* dinv   = (float*)(offs + Npad + 64);            // [Npad]
  size_t need = (size_t)((char*)(dinv + Npad) - (char*)d_ws);
  if (need > ws_size) return;  // fail loudly rather than corrupt

  // ---- graph preprocessing: window bucket + window-local counting sort ----
  k_cnt<<<SBLK, 256, 0, stream>>>(ei, cnt512, E, nw);
  k_scanA<<<nw, 512, 0, stream>>>(cnt512, wtot, nw);
  k_scanB<<<1, 512, 0, stream>>>(wtot, woffs, nw, E);
  k_append<<<SBLK, 256, 0, stream>>>(ei, cnt512, woffs, bucket, E, nw);
  k_sortw<<<nw, 256, 0, stream>>>(bucket, woffs, csr, offs, dinv, N, E);

  // ---- layer 1 ----
  k_gemm1<<<(N + 127) / 128, 256, 0, stream>>>(x, W1, bufA, N);
  k_gath<<<(N * 64 + 255) / 256, 256, 0, stream>>>(csr, offs, dinv, bufA,
                                                   b1, g1, be1, m1, v1, bufB, N);
  // ---- layer 2 ----
  k_gemm2<<<(N + 127) / 128, 256, 0, stream>>>(bufB, W2, bufA, N);
  k_gath<<<(N * 64 + 255) / 256, 256, 0, stream>>>(csr, offs, dinv, bufA,
                                                   b2, g2, be2, m2, v2, bufB, N);
  // ---- classifier head ----
  k_cls<<<(N + 255) / 256, 256, 0, stream>>>(bufB, Wc1, bc1, Wc2, bc2, out, N);
}